// Round 4
// baseline (120.831 us; speedup 1.0000x reference)
//
#include <hip/hip_runtime.h>

#define NI 8
#define NF 100
#define NH 40
#define NC 40
#define NM 41
#define BSZ 2048
#define BT 64
#define XPAD 104   // x-tile LDS row stride (floats), zero-padded 100..103

typedef __attribute__((ext_vector_type(8))) short bf16x8;
typedef __attribute__((ext_vector_type(4))) float f32x4;
typedef __attribute__((ext_vector_type(4))) unsigned int u32x4;

__device__ __forceinline__ unsigned short f2bf(float f) {
    unsigned int u = __builtin_bit_cast(unsigned int, f);
    u += 0x7fffu + ((u >> 16) & 1u);
    return (unsigned short)(u >> 16);
}
__device__ __forceinline__ float bf2f(unsigned short s) {
    unsigned int u = ((unsigned int)s) << 16;
    return __builtin_bit_cast(float, u);
}
__device__ __forceinline__ bf16x8 pack8(float4 u, float4 v) {
    u32x4 w;
    w.x = (unsigned int)f2bf(u.x) | ((unsigned int)f2bf(u.y) << 16);
    w.y = (unsigned int)f2bf(u.z) | ((unsigned int)f2bf(u.w) << 16);
    w.z = (unsigned int)f2bf(v.x) | ((unsigned int)f2bf(v.y) << 16);
    w.w = (unsigned int)f2bf(v.z) | ((unsigned int)f2bf(v.w) << 16);
    return __builtin_bit_cast(bf16x8, w);
}

// ---------------------------------------------------------------------------
// K1: W_ic = A_ic @ B_ic (fp32, vectorized LDS), then emit bf16 MFMA B-frags.
//   Wb1: pass1 B operand, B[k=f][n=h], padded K=128, N=48.
//        [ic][nt(3)][k(4)][lane(64)] x 16B; n=nt*16+(lane&15), f=k*32+(lane>>4)*8+j
//   Wb2: pass2 B operand, B[k=h][n=f], padded K=64, N=112.
//        [ic][nt(7)][kk(2)][lane(64)] x 16B; n=nt*16+(lane&15), h=kk*32+(lane>>4)*8+j
// ---------------------------------------------------------------------------
__global__ __launch_bounds__(512) void build_w_kernel(
    const float* __restrict__ A, const float* __restrict__ Bp,
    unsigned short* __restrict__ Wb1, unsigned short* __restrict__ Wb2)
{
    __shared__ __align__(16) float As[NF * NM];
    __shared__ __align__(16) float Bs[NM * NH];
    __shared__ __align__(16) float Ws[NF * NH];
    const int ic = blockIdx.x;  // i*NC + c
    const float* Ap  = A  + (size_t)ic * NF * NM;
    const float* Bpp = Bp + (size_t)ic * NM * NH;
    for (int idx = threadIdx.x; idx < NF * NM; idx += 512) As[idx] = Ap[idx];
    for (int idx = threadIdx.x; idx < NM * NH; idx += 512) Bs[idx] = Bpp[idx];
    __syncthreads();
    // vectorized: thread computes 4 h's (one float4) per item
    for (int idx = threadIdx.x; idx < NF * (NH / 4); idx += 512) {
        const int f  = idx / (NH / 4);
        const int hq = idx % (NH / 4);
        float4 acc = make_float4(0.f, 0.f, 0.f, 0.f);
        #pragma unroll
        for (int m = 0; m < NM; ++m) {
            const float  a = As[f * NM + m];
            const float4 b = *(const float4*)&Bs[m * NH + hq * 4];
            acc.x += a * b.x; acc.y += a * b.y; acc.z += a * b.z; acc.w += a * b.w;
        }
        *(float4*)&Ws[f * NH + hq * 4] = acc;
    }
    __syncthreads();

    // Wb1 fragments: 3*4*64 = 768 entries of 16B
    for (int e = threadIdx.x; e < 768; e += 512) {
        const int nt = e >> 8, k = (e >> 6) & 3, ln = e & 63;
        const int col = ln & 15, quad = ln >> 4;
        const int h = nt * 16 + col;
        unsigned int w[4];
        #pragma unroll
        for (int jj = 0; jj < 4; ++jj) {
            const int f0 = k * 32 + quad * 8 + jj * 2;
            const int f1 = f0 + 1;
            const unsigned int lo = (f0 < NF && h < NH) ? f2bf(Ws[f0 * NH + h]) : 0;
            const unsigned int hi = (f1 < NF && h < NH) ? f2bf(Ws[f1 * NH + h]) : 0;
            w[jj] = lo | (hi << 16);
        }
        ((u32x4*)Wb1)[(size_t)ic * 768 + e] = (u32x4){w[0], w[1], w[2], w[3]};
    }
    // Wb2 fragments: 7*2*64 = 896 entries of 16B
    for (int e = threadIdx.x; e < 896; e += 512) {
        const int nt = e >> 7, kk = (e >> 6) & 1, ln = e & 63;
        const int col = ln & 15, quad = ln >> 4;
        const int f = nt * 16 + col;
        unsigned int w[4];
        #pragma unroll
        for (int jj = 0; jj < 4; ++jj) {
            const int h0 = kk * 32 + quad * 8 + jj * 2;
            const int h1 = h0 + 1;
            const unsigned int lo = (f < NF && h0 < NH) ? f2bf(Ws[f * NH + h0]) : 0;
            const unsigned int hi = (f < NF && h1 < NH) ? f2bf(Ws[f * NH + h1]) : 0;
            w[jj] = lo | (hi << 16);
        }
        ((u32x4*)Wb2)[(size_t)ic * 896 + e] = (u32x4){w[0], w[1], w[2], w[3]};
    }
}

// ---------------------------------------------------------------------------
// Fused MFMA kernel. One block = (64 b's, one i). 512 threads = 8 waves.
// B-fragments stream from L2 with register double-buffer prefetch so the
// c-loops overlap load latency with MFMA. First prefetch of each pass is
// issued before the preceding LDS phase so cold latency overlaps staging.
// ---------------------------------------------------------------------------
__global__ __launch_bounds__(512, 2) void fused_kernel(
    const float* __restrict__ x, const float* __restrict__ mask,
    const float* __restrict__ b_final,
    const unsigned short* __restrict__ Wb1, const unsigned short* __restrict__ Wb2,
    float* __restrict__ out)
{
    __shared__ unsigned char msx[BT * NC];                   // 2560 B, 0/1 mask
    __shared__ __align__(16) unsigned char regionB[57344];   // union:
    // phase A: xs[b(64)][XPAD(104)] fp32 (26624 B)
    // phase B: hsP[g(8)][b(64)][h(48)] bf16 (49152 B)
    // phase C: outP[hb(2)][p(4)][bl(32)][f(112)] bf16 (57344 B)
    unsigned short* region = (unsigned short*)regionB;
    float* xs = (float*)regionB;

    const int tid  = threadIdx.x;
    const int lane = tid & 63;
    const int wav  = tid >> 6;       // 0..7
    const int col  = lane & 15;
    const int quad = lane >> 4;
    const int hb   = wav >> 2;       // pass2 b-half
    const int cp   = wav & 3;        // pass2 c-phase
    const int i    = blockIdx.x % NI;
    const int b0   = (blockIdx.x / NI) * BT;

    const u32x4* wb1i = (const u32x4*)Wb1 + (size_t)i * NC * 768;
    const u32x4* wb2i = (const u32x4*)Wb2 + (size_t)i * NC * 896;

    // ---- issue pass1 first B-frag prefetch (c = wav) before anything else ----
    u32x4 bufA[12], bufB[12];
    {
        const u32x4* p = wb1i + (size_t)wav * 768;
        #pragma unroll
        for (int e = 0; e < 12; ++e) bufA[e] = p[e * 64 + lane];
    }

    // ---- stage mask tile (bytes) + x tile (coalesced float4, rows padded) ----
    for (int idx = tid; idx < BT * NC; idx += 512) {
        const int b = idx / NC, c = idx % NC;
        msx[idx] = mask[((size_t)(b0 + b) * NI + i) * NC + c] > 0.5f ? 1 : 0;
    }
    for (int idx = tid; idx < BT * (XPAD / 4); idx += 512) {
        const int row = idx / (XPAD / 4), fq = idx % (XPAD / 4);
        float4 v = make_float4(0.f, 0.f, 0.f, 0.f);
        if (fq < NF / 4)
            v = *(const float4*)(x + ((size_t)(b0 + row) * NI + i) * NF + fq * 4);
        *(float4*)&xs[row * XPAD + fq * 4] = v;
    }
    __syncthreads();

    // ---- build X A-fragments from LDS: a1[mt][k], M=64, K=128(pad) ----
    bf16x8 a1[4][4];
    #pragma unroll
    for (int mt = 0; mt < 4; ++mt) {
        const float* xr = xs + (mt * 16 + col) * XPAD;
        #pragma unroll
        for (int k = 0; k < 4; ++k) {
            const int f0 = k * 32 + quad * 8;
            if (k < 3 || quad == 0) {
                const float4 u = *(const float4*)(xr + f0);
                const float4 v = *(const float4*)(xr + f0 + 4);
                a1[mt][k] = pack8(u, v);  // f=96..103: 100..103 are zero pad
            } else {
                a1[mt][k] = __builtin_bit_cast(bf16x8, (u32x4){0, 0, 0, 0});
            }
        }
    }
    __syncthreads();  // all waves done reading xs before hsP overwrites region

    // ---- pass 1: H[mt][nt] accumulators (M=64, N=48) ----
    f32x4 H[4][3];
    #pragma unroll
    for (int mt = 0; mt < 4; ++mt)
        #pragma unroll
        for (int nt = 0; nt < 3; ++nt)
            H[mt][nt] = (f32x4){0.f, 0.f, 0.f, 0.f};

    #pragma unroll 1
    for (int cc = 0; cc < NC / 8; ++cc) {
        const int c = wav + cc * 8;
        if (cc < NC / 8 - 1) {  // prefetch next c into bufB
            const u32x4* p = wb1i + (size_t)(c + 8) * 768;
            #pragma unroll
            for (int e = 0; e < 12; ++e) bufB[e] = p[e * 64 + lane];
        }
        float mrow[4][4];
        #pragma unroll
        for (int mt = 0; mt < 4; ++mt)
            #pragma unroll
            for (int r = 0; r < 4; ++r)
                mrow[mt][r] = (float)msx[(mt * 16 + quad * 4 + r) * NC + c];
        #pragma unroll
        for (int mt = 0; mt < 4; ++mt) {
            #pragma unroll
            for (int nt = 0; nt < 3; ++nt) {
                f32x4 P = (f32x4){0.f, 0.f, 0.f, 0.f};
                #pragma unroll
                for (int k = 0; k < 4; ++k) {
                    P = __builtin_amdgcn_mfma_f32_16x16x32_bf16(
                        a1[mt][k], __builtin_bit_cast(bf16x8, bufA[nt * 4 + k]), P, 0, 0, 0);
                }
                #pragma unroll
                for (int r = 0; r < 4; ++r)
                    H[mt][nt][r] += mrow[mt][r] * P[r];
            }
        }
        if (cc < NC / 8 - 1) {  // rotate buffers
            #pragma unroll
            for (int e = 0; e < 12; ++e) bufA[e] = bufB[e];
        }
    }

    // ---- issue pass2 first B-frag prefetch (c = cp) before LDS phases ----
    u32x4 buf2A[14], buf2B[14];
    {
        const u32x4* p = wb2i + (size_t)cp * 896;
        #pragma unroll
        for (int e = 0; e < 14; ++e) buf2A[e] = p[e * 64 + lane];
    }

    // ---- write per-wave H partials (bf16): hsP[wav][b][h] ----
    #pragma unroll
    for (int mt = 0; mt < 4; ++mt)
        #pragma unroll
        for (int nt = 0; nt < 3; ++nt)
            #pragma unroll
            for (int r = 0; r < 4; ++r) {
                const int b = mt * 16 + quad * 4 + r;
                const int h = nt * 16 + col;
                region[(wav * 64 + b) * 48 + h] = f2bf(H[mt][nt][r]);
            }
    __syncthreads();

    // ---- 8-way reduce into slot 0; zero the h=40..47 pad columns ----
    for (int idx = tid; idx < BT * 48; idx += 512) {
        const int b = idx / 48, h = idx % 48;
        float s = 0.f;
        #pragma unroll
        for (int g = 0; g < 8; ++g) s += bf2f(region[(g * 64 + b) * 48 + h]);
        region[b * 48 + h] = (h < NH) ? f2bf(s) : (unsigned short)0;
    }
    __syncthreads();

    // ---- build pass2 A-frags via direct ds b128: a2[mt2][kk], K=40 pad 64 ----
    // (kk=1,quad>=1 reads stray LDS data; harmless — Wb2 B-side is zero there)
    bf16x8 a2[2][2];
    #pragma unroll
    for (int mt2 = 0; mt2 < 2; ++mt2) {
        const int b = hb * 32 + mt2 * 16 + col;
        #pragma unroll
        for (int kk = 0; kk < 2; ++kk)
            a2[mt2][kk] = *(const bf16x8*)&region[b * 48 + kk * 32 + quad * 8];
    }
    __syncthreads();  // everyone done reading hsP before outP overwrites region

    // ---- pass 2: O[mt2][nt] accumulators (M=32, N=112) ----
    f32x4 O[2][7];
    #pragma unroll
    for (int mt2 = 0; mt2 < 2; ++mt2)
        #pragma unroll
        for (int nt = 0; nt < 7; ++nt)
            O[mt2][nt] = (f32x4){0.f, 0.f, 0.f, 0.f};

    #pragma unroll 1
    for (int cc = 0; cc < NC / 4; ++cc) {
        const int c = cp + cc * 4;
        if (cc < NC / 4 - 1) {  // prefetch next c into buf2B
            const u32x4* p = wb2i + (size_t)(c + 4) * 896;
            #pragma unroll
            for (int e = 0; e < 14; ++e) buf2B[e] = p[e * 64 + lane];
        }
        float mrow2[2][4];
        #pragma unroll
        for (int mt2 = 0; mt2 < 2; ++mt2)
            #pragma unroll
            for (int r = 0; r < 4; ++r)
                mrow2[mt2][r] = (float)msx[(hb * 32 + mt2 * 16 + quad * 4 + r) * NC + c];
        #pragma unroll
        for (int mt2 = 0; mt2 < 2; ++mt2) {
            #pragma unroll
            for (int nt = 0; nt < 7; ++nt) {
                f32x4 P = (f32x4){0.f, 0.f, 0.f, 0.f};
                #pragma unroll
                for (int kk = 0; kk < 2; ++kk) {
                    P = __builtin_amdgcn_mfma_f32_16x16x32_bf16(
                        a2[mt2][kk], __builtin_bit_cast(bf16x8, buf2A[nt * 2 + kk]), P, 0, 0, 0);
                }
                #pragma unroll
                for (int r = 0; r < 4; ++r)
                    O[mt2][nt][r] += mrow2[mt2][r] * P[r];
            }
        }
        if (cc < NC / 4 - 1) {  // rotate buffers
            #pragma unroll
            for (int e = 0; e < 14; ++e) buf2A[e] = buf2B[e];
        }
    }

    // ---- write out partials (bf16): outP[hb][cp][bl][f] ----
    #pragma unroll
    for (int mt2 = 0; mt2 < 2; ++mt2)
        #pragma unroll
        for (int nt = 0; nt < 7; ++nt)
            #pragma unroll
            for (int r = 0; r < 4; ++r) {
                const int bl = mt2 * 16 + quad * 4 + r;
                const int f  = nt * 16 + col;
                region[((hb * 4 + cp) * 32 + bl) * 112 + f] = f2bf(O[mt2][nt][r]);
            }
    __syncthreads();

    // ---- final: 4-way reduce + bias + relu, coalesced store ----
    for (int idx = tid; idx < BT * NF; idx += 512) {
        const int b = idx / NF, f = idx % NF;
        const int hb2 = b >> 5, bl = b & 31;
        float s = 0.f;
        #pragma unroll
        for (int p = 0; p < 4; ++p)
            s += bf2f(region[((hb2 * 4 + p) * 32 + bl) * 112 + f]);
        const float v = s + b_final[i * NF + f];
        out[((size_t)(b0 + b) * NI + i) * NF + f] = fmaxf(v, 0.f);
    }
}

extern "C" void kernel_launch(void* const* d_in, const int* in_sizes, int n_in,
                              void* d_out, int out_size, void* d_ws, size_t ws_size,
                              hipStream_t stream) {
    const float* x       = (const float*)d_in[0];  // (2048, 8, 100)
    const float* tk_mask = (const float*)d_in[1];  // (2048, 8, 40)
    const float* A       = (const float*)d_in[2];  // (8, 40, 100, 41)
    const float* Bp      = (const float*)d_in[3];  // (8, 40, 41, 40)
    const float* b_final = (const float*)d_in[4];  // (8, 100)
    float* out = (float*)d_out;                    // (2048, 8, 100)

    unsigned short* Wb1 = (unsigned short*)d_ws;
    unsigned short* Wb2 = Wb1 + (size_t)NI * NC * 768 * 8;

    build_w_kernel<<<NI * NC, 512, 0, stream>>>(A, Bp, Wb1, Wb2);
    fused_kernel<<<(BSZ / BT) * NI, 512, 0, stream>>>(x, tk_mask, b_final, Wb1, Wb2, out);
}

// Round 5
// 109.514 us; speedup vs baseline: 1.1033x; 1.1033x over previous
//
#include <hip/hip_runtime.h>

#define NI 8
#define NF 100
#define NH 40
#define NC 40
#define NM 41
#define BSZ 2048
#define BT 64
#define XPAD 104   // x-tile LDS row stride (floats), zero-padded 100..103

typedef __attribute__((ext_vector_type(8))) short bf16x8;
typedef __attribute__((ext_vector_type(4))) float f32x4;
typedef __attribute__((ext_vector_type(4))) unsigned int u32x4;

__device__ __forceinline__ unsigned short f2bf(float f) {
    unsigned int u = __builtin_bit_cast(unsigned int, f);
    u += 0x7fffu + ((u >> 16) & 1u);
    return (unsigned short)(u >> 16);
}
__device__ __forceinline__ float bf2f(unsigned short s) {
    unsigned int u = ((unsigned int)s) << 16;
    return __builtin_bit_cast(float, u);
}
__device__ __forceinline__ bf16x8 pack8(float4 u, float4 v) {
    u32x4 w;
    w.x = (unsigned int)f2bf(u.x) | ((unsigned int)f2bf(u.y) << 16);
    w.y = (unsigned int)f2bf(u.z) | ((unsigned int)f2bf(u.w) << 16);
    w.z = (unsigned int)f2bf(v.x) | ((unsigned int)f2bf(v.y) << 16);
    w.w = (unsigned int)f2bf(v.z) | ((unsigned int)f2bf(v.w) << 16);
    return __builtin_bit_cast(bf16x8, w);
}

// ---------------------------------------------------------------------------
// K1: W_ic = A_ic @ B_ic (fp32, vectorized LDS), then emit bf16 MFMA B-frags.
//   Wb1: pass1 B operand, B[k=f][n=h], padded K=128, N=48.
//        [ic][nt(3)][k(4)][lane(64)] x 16B; n=nt*16+(lane&15), f=k*32+(lane>>4)*8+j
//   Wb2: pass2 B operand, B[k=h][n=f], padded K=64, N=112.
//        [ic][nt(7)][kk(2)][lane(64)] x 16B; n=nt*16+(lane&15), h=kk*32+(lane>>4)*8+j
// ---------------------------------------------------------------------------
__global__ __launch_bounds__(512) void build_w_kernel(
    const float* __restrict__ A, const float* __restrict__ Bp,
    unsigned short* __restrict__ Wb1, unsigned short* __restrict__ Wb2)
{
    __shared__ __align__(16) float As[NF * NM];
    __shared__ __align__(16) float Bs[NM * NH];
    __shared__ __align__(16) float Ws[NF * NH];
    const int ic = blockIdx.x;  // i*NC + c
    const float* Ap  = A  + (size_t)ic * NF * NM;
    const float* Bpp = Bp + (size_t)ic * NM * NH;
    for (int idx = threadIdx.x; idx < NF * NM; idx += 512) As[idx] = Ap[idx];
    for (int idx = threadIdx.x; idx < NM * NH; idx += 512) Bs[idx] = Bpp[idx];
    __syncthreads();
    // vectorized: thread computes 4 h's (one float4) per item
    for (int idx = threadIdx.x; idx < NF * (NH / 4); idx += 512) {
        const int f  = idx / (NH / 4);
        const int hq = idx % (NH / 4);
        float4 acc = make_float4(0.f, 0.f, 0.f, 0.f);
        #pragma unroll
        for (int m = 0; m < NM; ++m) {
            const float  a = As[f * NM + m];
            const float4 b = *(const float4*)&Bs[m * NH + hq * 4];
            acc.x += a * b.x; acc.y += a * b.y; acc.z += a * b.z; acc.w += a * b.w;
        }
        *(float4*)&Ws[f * NH + hq * 4] = acc;
    }
    __syncthreads();

    // Wb1 fragments: 3*4*64 = 768 entries of 16B
    for (int e = threadIdx.x; e < 768; e += 512) {
        const int nt = e >> 8, k = (e >> 6) & 3, ln = e & 63;
        const int col = ln & 15, quad = ln >> 4;
        const int h = nt * 16 + col;
        unsigned int w[4];
        #pragma unroll
        for (int jj = 0; jj < 4; ++jj) {
            const int f0 = k * 32 + quad * 8 + jj * 2;
            const int f1 = f0 + 1;
            const unsigned int lo = (f0 < NF && h < NH) ? f2bf(Ws[f0 * NH + h]) : 0;
            const unsigned int hi = (f1 < NF && h < NH) ? f2bf(Ws[f1 * NH + h]) : 0;
            w[jj] = lo | (hi << 16);
        }
        ((u32x4*)Wb1)[(size_t)ic * 768 + e] = (u32x4){w[0], w[1], w[2], w[3]};
    }
    // Wb2 fragments: 7*2*64 = 896 entries of 16B
    for (int e = threadIdx.x; e < 896; e += 512) {
        const int nt = e >> 7, kk = (e >> 6) & 1, ln = e & 63;
        const int col = ln & 15, quad = ln >> 4;
        const int f = nt * 16 + col;
        unsigned int w[4];
        #pragma unroll
        for (int jj = 0; jj < 4; ++jj) {
            const int h0 = kk * 32 + quad * 8 + jj * 2;
            const int h1 = h0 + 1;
            const unsigned int lo = (f < NF && h0 < NH) ? f2bf(Ws[f * NH + h0]) : 0;
            const unsigned int hi = (f < NF && h1 < NH) ? f2bf(Ws[f * NH + h1]) : 0;
            w[jj] = lo | (hi << 16);
        }
        ((u32x4*)Wb2)[(size_t)ic * 896 + e] = (u32x4){w[0], w[1], w[2], w[3]};
    }
}

// ---------------------------------------------------------------------------
// Fused MFMA kernel. One block = (64 b's, one i). 512 threads = 8 waves.
// B-fragments stream from L2 with IN-PLACE rolling reload: after each
// nt-group's fragments are fully consumed, the same register slots are
// reloaded with the next c's fragments (1-iter lookahead, no rotation movs,
// no double buffer => fits under the 256-VGPR / 2-waves-per-SIMD budget).
// __launch_bounds__(512,1): round-4's (512,2) capped VGPR at 128 -> 23 MB of
// scratch spills (WRITE_SIZE 30 MB vs 6.5 MB output).
// ---------------------------------------------------------------------------
__global__ __launch_bounds__(512, 1) void fused_kernel(
    const float* __restrict__ x, const float* __restrict__ mask,
    const float* __restrict__ b_final,
    const unsigned short* __restrict__ Wb1, const unsigned short* __restrict__ Wb2,
    float* __restrict__ out)
{
    __shared__ unsigned char msx[BT * NC];                   // 2560 B, 0/1 mask
    __shared__ __align__(16) unsigned char regionB[57344];   // union:
    // phase A: xs[b(64)][XPAD(104)] fp32 (26624 B)
    // phase B: hsP[g(8)][b(64)][h(48)] bf16 (49152 B)
    // phase C: outP[hb(2)][p(4)][bl(32)][f(112)] bf16 (57344 B)
    unsigned short* region = (unsigned short*)regionB;
    float* xs = (float*)regionB;

    const int tid  = threadIdx.x;
    const int lane = tid & 63;
    const int wav  = tid >> 6;       // 0..7
    const int col  = lane & 15;
    const int quad = lane >> 4;
    const int hb   = wav >> 2;       // pass2 b-half
    const int cp   = wav & 3;        // pass2 c-phase
    const int i    = blockIdx.x % NI;
    const int b0   = (blockIdx.x / NI) * BT;

    const u32x4* wb1i = (const u32x4*)Wb1 + (size_t)i * NC * 768;
    const u32x4* wb2i = (const u32x4*)Wb2 + (size_t)i * NC * 896;

    // ---- issue pass1 first B-frag prefetch (c = wav) before anything else ----
    u32x4 bufA[12];
    {
        const u32x4* p = wb1i + (size_t)wav * 768;
        #pragma unroll
        for (int e = 0; e < 12; ++e) bufA[e] = p[e * 64 + lane];
    }

    // ---- stage mask tile (bytes) + x tile (coalesced float4, rows padded) ----
    for (int idx = tid; idx < BT * NC; idx += 512) {
        const int b = idx / NC, c = idx % NC;
        msx[idx] = mask[((size_t)(b0 + b) * NI + i) * NC + c] > 0.5f ? 1 : 0;
    }
    for (int idx = tid; idx < BT * (XPAD / 4); idx += 512) {
        const int row = idx / (XPAD / 4), fq = idx % (XPAD / 4);
        float4 v = make_float4(0.f, 0.f, 0.f, 0.f);
        if (fq < NF / 4)
            v = *(const float4*)(x + ((size_t)(b0 + row) * NI + i) * NF + fq * 4);
        *(float4*)&xs[row * XPAD + fq * 4] = v;
    }
    __syncthreads();

    // ---- build X A-fragments from LDS: a1[mt][k], M=64, K=128(pad) ----
    bf16x8 a1[4][4];
    #pragma unroll
    for (int mt = 0; mt < 4; ++mt) {
        const float* xr = xs + (mt * 16 + col) * XPAD;
        #pragma unroll
        for (int k = 0; k < 4; ++k) {
            const int f0 = k * 32 + quad * 8;
            if (k < 3 || quad == 0) {
                const float4 u = *(const float4*)(xr + f0);
                const float4 v = *(const float4*)(xr + f0 + 4);
                a1[mt][k] = pack8(u, v);  // f=96..103: 100..103 are zero pad
            } else {
                a1[mt][k] = __builtin_bit_cast(bf16x8, (u32x4){0, 0, 0, 0});
            }
        }
    }
    __syncthreads();  // all waves done reading xs before hsP overwrites region

    // ---- pass 1: H[mt][nt] accumulators (M=64, N=48) ----
    f32x4 H[4][3];
    #pragma unroll
    for (int mt = 0; mt < 4; ++mt)
        #pragma unroll
        for (int nt = 0; nt < 3; ++nt)
            H[mt][nt] = (f32x4){0.f, 0.f, 0.f, 0.f};

    #pragma unroll 1
    for (int cc = 0; cc < NC / 8; ++cc) {
        const int c = wav + cc * 8;
        float mrow[4][4];
        #pragma unroll
        for (int mt = 0; mt < 4; ++mt)
            #pragma unroll
            for (int r = 0; r < 4; ++r)
                mrow[mt][r] = (float)msx[(mt * 16 + quad * 4 + r) * NC + c];
        #pragma unroll
        for (int nt = 0; nt < 3; ++nt) {
            #pragma unroll
            for (int mt = 0; mt < 4; ++mt) {
                f32x4 P = (f32x4){0.f, 0.f, 0.f, 0.f};
                #pragma unroll
                for (int k = 0; k < 4; ++k) {
                    P = __builtin_amdgcn_mfma_f32_16x16x32_bf16(
                        a1[mt][k], __builtin_bit_cast(bf16x8, bufA[nt * 4 + k]), P, 0, 0, 0);
                }
                #pragma unroll
                for (int r = 0; r < 4; ++r)
                    H[mt][nt][r] += mrow[mt][r] * P[r];
            }
            // nt-group fully consumed -> reload same slots with next c's frags
            if (cc < NC / 8 - 1) {
                const u32x4* p = wb1i + (size_t)(c + 8) * 768;
                #pragma unroll
                for (int k = 0; k < 4; ++k)
                    bufA[nt * 4 + k] = p[(nt * 4 + k) * 64 + lane];
            }
        }
    }

    // ---- issue pass2 first B-frag prefetch (c = cp) before LDS phases ----
    u32x4 buf2A[14];
    {
        const u32x4* p = wb2i + (size_t)cp * 896;
        #pragma unroll
        for (int e = 0; e < 14; ++e) buf2A[e] = p[e * 64 + lane];
    }

    // ---- write per-wave H partials (bf16): hsP[wav][b][h] ----
    #pragma unroll
    for (int mt = 0; mt < 4; ++mt)
        #pragma unroll
        for (int nt = 0; nt < 3; ++nt)
            #pragma unroll
            for (int r = 0; r < 4; ++r) {
                const int b = mt * 16 + quad * 4 + r;
                const int h = nt * 16 + col;
                region[(wav * 64 + b) * 48 + h] = f2bf(H[mt][nt][r]);
            }
    __syncthreads();

    // ---- 8-way reduce into slot 0; zero the h=40..47 pad columns ----
    for (int idx = tid; idx < BT * 48; idx += 512) {
        const int b = idx / 48, h = idx % 48;
        float s = 0.f;
        #pragma unroll
        for (int g = 0; g < 8; ++g) s += bf2f(region[(g * 64 + b) * 48 + h]);
        region[b * 48 + h] = (h < NH) ? f2bf(s) : (unsigned short)0;
    }
    __syncthreads();

    // ---- build pass2 A-frags via direct ds b128: a2[mt2][kk], K=40 pad 64 ----
    bf16x8 a2[2][2];
    #pragma unroll
    for (int mt2 = 0; mt2 < 2; ++mt2) {
        const int b = hb * 32 + mt2 * 16 + col;
        #pragma unroll
        for (int kk = 0; kk < 2; ++kk)
            a2[mt2][kk] = *(const bf16x8*)&region[b * 48 + kk * 32 + quad * 8];
    }
    __syncthreads();  // everyone done reading hsP before outP overwrites region

    // ---- pass 2: O[mt2][nt] accumulators (M=32, N=112) ----
    f32x4 O[2][7];
    #pragma unroll
    for (int mt2 = 0; mt2 < 2; ++mt2)
        #pragma unroll
        for (int nt = 0; nt < 7; ++nt)
            O[mt2][nt] = (f32x4){0.f, 0.f, 0.f, 0.f};

    #pragma unroll 1
    for (int cc = 0; cc < NC / 4; ++cc) {
        const int c = cp + cc * 4;
        float mrow2[2][4];
        #pragma unroll
        for (int mt2 = 0; mt2 < 2; ++mt2)
            #pragma unroll
            for (int r = 0; r < 4; ++r)
                mrow2[mt2][r] = (float)msx[(hb * 32 + mt2 * 16 + quad * 4 + r) * NC + c];
        #pragma unroll
        for (int nt = 0; nt < 7; ++nt) {
            #pragma unroll
            for (int mt2 = 0; mt2 < 2; ++mt2) {
                f32x4 P = (f32x4){0.f, 0.f, 0.f, 0.f};
                #pragma unroll
                for (int kk = 0; kk < 2; ++kk) {
                    P = __builtin_amdgcn_mfma_f32_16x16x32_bf16(
                        a2[mt2][kk], __builtin_bit_cast(bf16x8, buf2A[nt * 2 + kk]), P, 0, 0, 0);
                }
                #pragma unroll
                for (int r = 0; r < 4; ++r)
                    O[mt2][nt][r] += mrow2[mt2][r] * P[r];
            }
            // nt-group consumed -> reload same slots with next c's frags
            if (cc < NC / 4 - 1) {
                const u32x4* p = wb2i + (size_t)(c + 4) * 896;
                #pragma unroll
                for (int kk = 0; kk < 2; ++kk)
                    buf2A[nt * 2 + kk] = p[(nt * 2 + kk) * 64 + lane];
            }
        }
    }

    // ---- write out partials (bf16): outP[hb][cp][bl][f] ----
    #pragma unroll
    for (int mt2 = 0; mt2 < 2; ++mt2)
        #pragma unroll
        for (int nt = 0; nt < 7; ++nt)
            #pragma unroll
            for (int r = 0; r < 4; ++r) {
                const int bl = mt2 * 16 + quad * 4 + r;
                const int f  = nt * 16 + col;
                region[((hb * 4 + cp) * 32 + bl) * 112 + f] = f2bf(O[mt2][nt][r]);
            }
    __syncthreads();

    // ---- final: 4-way reduce + bias + relu, coalesced store ----
    for (int idx = tid; idx < BT * NF; idx += 512) {
        const int b = idx / NF, f = idx % NF;
        const int hb2 = b >> 5, bl = b & 31;
        float s = 0.f;
        #pragma unroll
        for (int p = 0; p < 4; ++p)
            s += bf2f(region[((hb2 * 4 + p) * 32 + bl) * 112 + f]);
        const float v = s + b_final[i * NF + f];
        out[((size_t)(b0 + b) * NI + i) * NF + f] = fmaxf(v, 0.f);
    }
}

extern "C" void kernel_launch(void* const* d_in, const int* in_sizes, int n_in,
                              void* d_out, int out_size, void* d_ws, size_t ws_size,
                              hipStream_t stream) {
    const float* x       = (const float*)d_in[0];  // (2048, 8, 100)
    const float* tk_mask = (const float*)d_in[1];  // (2048, 8, 40)
    const float* A       = (const float*)d_in[2];  // (8, 40, 100, 41)
    const float* Bp      = (const float*)d_in[3];  // (8, 40, 41, 40)
    const float* b_final = (const float*)d_in[4];  // (8, 100)
    float* out = (float*)d_out;                    // (2048, 8, 100)

    unsigned short* Wb1 = (unsigned short*)d_ws;
    unsigned short* Wb2 = Wb1 + (size_t)NI * NC * 768 * 8;

    build_w_kernel<<<NI * NC, 512, 0, stream>>>(A, Bp, Wb1, Wb2);
    fused_kernel<<<(BSZ / BT) * NI, 512, 0, stream>>>(x, tk_mask, b_final, Wb1, Wb2, out);
}